// Round 3
// baseline (547.588 us; speedup 1.0000x reference)
//
#include <hip/hip_runtime.h>

// BasicMotionEncoder (RAFT): B=8, H=96, W=128, CORR=324.
// Round 8 (resubmit — round 2's bench was an infra failure, no counters):
//  - conv2 <256,6>: launch_bounds(256,3) -> target 3 blocks/CU so the 768
//    blocks are exactly resident in ONE phase (was 2-resident -> 1.5-phase
//    tail, 17.7% occupancy). setprio kept (+13% in round 1).
//  - convf1 reverted to NF=8 grid(384,1): splitting a K=128 1x1 doubled
//    epilogue/prologue fixed costs (net regression in round 7).
//  - conv5 <256,4> and convf2 <128,2> keep grid(384,2) 3-resident shape.
//  - setprio added around mfma_gemm's MFMA cluster (conv1, convf1).

typedef __bf16 bf16x8 __attribute__((ext_vector_type(8)));
typedef float f32x4 __attribute__((ext_vector_type(4)));

__device__ __forceinline__ unsigned short f2bf(float f) {
  __bf16 h = (__bf16)f;
  return __builtin_bit_cast(unsigned short, h);
}
__device__ __forceinline__ float bf2f(unsigned short u) {
  __bf16 h = __builtin_bit_cast(__bf16, u);
  return (float)h;
}

__device__ __forceinline__ void gload_lds16(const unsigned short* g,
                                            unsigned short* l) {
  __builtin_amdgcn_global_load_lds(
      (const __attribute__((address_space(1))) unsigned int*)g,
      (__attribute__((address_space(3))) unsigned int*)l, 16, 0, 0);
}

// ---------------- weight repack: OIHW f32 -> [tap][icq][OCP][8] bf16 ---------
__global__ __launch_bounds__(256) void repack_w_bf16(
    const float* __restrict__ w, unsigned short* __restrict__ dst, int O, int I,
    int K2, int ICQ, int OCP) {
  int n = K2 * ICQ * OCP * 8;
  for (int s = blockIdx.x * 256 + threadIdx.x; s < n; s += gridDim.x * 256) {
    int j = s & 7;
    int r = s >> 3;
    int oc = r % OCP;
    r /= OCP;
    int icq = r % ICQ;
    int tap = r / ICQ;
    int ic = icq * 8 + j;
    float v = (oc < O && ic < I) ? w[((size_t)oc * I + ic) * K2 + tap] : 0.f;
    dst[s] = f2bf(v);
  }
}

// wf1 [128][2][7][7] -> [kq=16][128][8], k = ic*49 + dy*7 + dx, pad 98->128
__global__ __launch_bounds__(256) void repack_wf1(const float* __restrict__ w,
                                                  unsigned short* __restrict__ dst) {
  int s = blockIdx.x * 256 + threadIdx.x;
  if (s >= 16384) return;
  int j = s & 7;
  int oc = (s >> 3) & 127;
  int kq = s >> 10;
  int k = kq * 8 + j;
  float v = 0.f;
  if (k < 98) {
    int ic = k / 49;
    int tap = k - ic * 49;
    v = w[(oc * 2 + ic) * 49 + tap];
  }
  dst[s] = f2bf(v);
}

// ------------- NCHW f32 -> NHWC bf16 (zero-padded channels) ------------------
__global__ __launch_bounds__(256) void nchw2nhwc_bf16(
    const float* __restrict__ in, unsigned short* __restrict__ outp, int C,
    int CP, int HW) {
  __shared__ float sls[64][65];
  int p0 = blockIdx.x * 64;
  int c0 = blockIdx.y * 64;
  int b = p0 / HW, hw0 = p0 % HW;
  int tid = threadIdx.x;
  for (int e = tid; e < 4096; e += 256) {
    int ch = e >> 6, px = e & 63;
    float v = 0.f;
    if (c0 + ch < C) v = in[(size_t)(b * C + c0 + ch) * HW + hw0 + px];
    sls[px][ch] = v;
  }
  __syncthreads();
  for (int e = tid; e < 512; e += 256) {
    int px = e >> 3, cc = e & 7;
    if (c0 + cc * 8 < CP) {
      unsigned short pk[8];
#pragma unroll
      for (int j = 0; j < 8; ++j) pk[j] = f2bf(sls[px][cc * 8 + j]);
      *(uint4*)&outp[(size_t)(p0 + px) * CP + c0 + cc * 8] = *(uint4*)pk;
    }
  }
}

// ------------- NHWC bf16 -> NCHW f32 (channels < CO only) --------------------
__global__ __launch_bounds__(256) void nhwc_bf16_2nchw(
    const unsigned short* __restrict__ inp, float* __restrict__ outp, int CP,
    int CO, int CT, int HW) {
  __shared__ float sls[64][65];
  int p0 = blockIdx.x * 64, c0 = blockIdx.y * 64;
  int b = p0 / HW, hw0 = p0 % HW;
  int tid = threadIdx.x;
  for (int e = tid; e < 512; e += 256) {
    int px = e >> 3, cc = e & 7;
    uint4 v = *(const uint4*)&inp[(size_t)(p0 + px) * CP + c0 + cc * 8];
    unsigned short* ps = (unsigned short*)&v;
#pragma unroll
    for (int j = 0; j < 8; ++j) sls[px][cc * 8 + j] = bf2f(ps[j]);
  }
  __syncthreads();
  for (int e = tid; e < 1024; e += 256) {
    int ch = e >> 4, pq = e & 15;
    if (c0 + ch < CO) {
      float4 v;
      v.x = sls[pq * 4 + 0][ch];
      v.y = sls[pq * 4 + 1][ch];
      v.z = sls[pq * 4 + 2][ch];
      v.w = sls[pq * 4 + 3][ch];
      *(float4*)&outp[(size_t)(b * CT + c0 + ch) * HW + hw0 + pq * 4] = v;
    }
  }
}

// ------------- zero the 1-px halo border of the 3 padded buffers -------------
__global__ __launch_bounds__(256) void zero_halo3(unsigned short* b0,
                                                  unsigned short* b1,
                                                  unsigned short* b2) {
  unsigned short* buf = (blockIdx.y == 0) ? b0 : (blockIdx.y == 1) ? b1 : b2;
  const int C = (blockIdx.y == 2) ? 128 : 256;
  const int cq = C >> 3;
  int n = 8 * 452 * cq;
  int i = blockIdx.x * 256 + threadIdx.x;
  if (i >= n) return;
  int c = i % cq;
  int t = i / cq;
  int bp = t % 452;
  int bb = t / 452;
  int y, x;
  if (bp < 130) { y = 0; x = bp; }
  else if (bp < 260) { y = 97; x = bp - 130; }
  else { int r = bp - 260; y = 1 + (r >> 1); x = (r & 1) ? 129 : 0; }
  *(uint4*)&buf[((size_t)(bb * 98 + y) * 130 + x) * C + c * 8] =
      make_uint4(0, 0, 0, 0);
}

// ------------- im2col of flow: [8][2][96][128] f32 -> [NPX][128] bf16 --------
__global__ __launch_bounds__(256) void im2col_flow(const float* __restrict__ f,
                                                   unsigned short* __restrict__ o,
                                                   int H, int W) {
  int s = blockIdx.x * 256 + threadIdx.x;  // over NPX*16
  int kq = s & 15;
  int px = s >> 4;
  int HW = H * W;
  int b = px / HW;
  int r = px % HW;
  int y = r / W;
  int x = r % W;
  unsigned short pk[8];
#pragma unroll
  for (int j = 0; j < 8; ++j) {
    int k = kq * 8 + j;
    float v = 0.f;
    if (k < 98) {
      int ic = k / 49;
      int t = k - ic * 49;
      int dy = t / 7, dx = t - dy * 7;
      int yy = y + dy - 3, xx = x + dx - 3;
      if (yy >= 0 && yy < H && xx >= 0 && xx < W)
        v = f[((size_t)(b * 2 + ic) * H + yy) * W + xx];
    }
    pk[j] = f2bf(v);
  }
  *(uint4*)&o[(size_t)px * 128 + kq * 8] = *(uint4*)pk;
}

// =================== 1x1 MFMA GEMM (no LDS staging, no barriers) =============
// Block: 256 px x NF*16 oc; 4 waves x (64px x NF*16oc).
template <int CINP, int NF>
__global__ __launch_bounds__(256, (NF <= 4 ? 3 : 2)) void mfma_gemm(
    const unsigned short* __restrict__ xin,  // [B*H*W][CINP]
    const unsigned short* __restrict__ wpk,  // [CINP/8][OCP][8]
    const float* __restrict__ bias, unsigned short* __restrict__ yout,
    int H, int W, int Cout, int OCP, int CT, int coff, int Wo, int oh) {
  __shared__ __align__(16) unsigned short smem[NF * 2048];
  const int tid = threadIdx.x;
  const int wave = tid >> 6, lane = tid & 63;
  const int l15 = lane & 15, lq = lane >> 4;
  const int tilesX = W >> 4;
  const int perB = (H >> 4) * tilesX;
  const int b = blockIdx.x / perB;
  const int r0 = blockIdx.x % perB;
  const int ty0 = (r0 / tilesX) << 4;
  const int tx0 = (r0 % tilesX) << 4;
  const int oc0 = blockIdx.y * (NF * 16);

  f32x4 acc[4][NF];
#pragma unroll
  for (int mf = 0; mf < 4; ++mf)
#pragma unroll
    for (int nf = 0; nf < NF; ++nf) acc[mf][nf] = (f32x4){0.f, 0.f, 0.f, 0.f};

  size_t rowA[4];
#pragma unroll
  for (int mf = 0; mf < 4; ++mf)
    rowA[mf] =
        ((size_t)(b * H + ty0 + wave * 4 + mf) * W + tx0 + l15) * CINP + lq * 8;
  const unsigned short* wB = wpk + ((size_t)lq * OCP + oc0 + l15) * 8;
  const int icbStr = 4 * OCP * 8;

  constexpr int NI = CINP / 32;
#pragma unroll 2
  for (int icb = 0; icb < NI; ++icb) {
    bf16x8 va[4], vb[NF];
#pragma unroll
    for (int mf = 0; mf < 4; ++mf)
      va[mf] = *(const bf16x8*)&xin[rowA[mf] + icb * 32];
#pragma unroll
    for (int nf = 0; nf < NF; ++nf)
      vb[nf] = *(const bf16x8*)&wB[icb * icbStr + nf * 128];
    __builtin_amdgcn_s_setprio(1);
#pragma unroll
    for (int mf = 0; mf < 4; ++mf)
#pragma unroll
      for (int nf = 0; nf < NF; ++nf)
        acc[mf][nf] = __builtin_amdgcn_mfma_f32_16x16x32_bf16(
            va[mf], vb[nf], acc[mf][nf], 0, 0, 0);
    __builtin_amdgcn_s_setprio(0);
  }

  // two-pass epilogue: bias+relu, per-wave LDS transpose, 16B stores
  float bsv[NF];
#pragma unroll
  for (int nf = 0; nf < NF; ++nf) {
    int oc = oc0 + nf * 16 + l15;
    bsv[nf] = (oc < Cout) ? bias[oc] : 0.f;
  }
  unsigned short* slice = smem + wave * (NF * 512);
  const int Ho = H + 2 * oh;
#pragma unroll
  for (int pass = 0; pass < 2; ++pass) {
#pragma unroll
    for (int mf = 0; mf < 4; ++mf)
#pragma unroll
      for (int h = 0; h < NF / 2; ++h) {
        const int nf = pass * (NF / 2) + h;
#pragma unroll
        for (int r = 0; r < 4; ++r)
          slice[(mf * 16 + lq * 4 + r) * (NF * 8) + h * 16 + l15] =
              f2bf(fmaxf(acc[mf][nf][r] + bsv[nf], 0.f));
      }
#pragma unroll
    for (int j = 0; j < NF; ++j) {
      int c = j * 64 + lane;
      int pxl = c / NF;
      int ocq = (c - pxl * NF) * 8;
      uint4 v = *(uint4*)&slice[pxl * (NF * 8) + ocq];
      int pxg = wave * 64 + pxl;
      int gy = ty0 + (pxg >> 4) + oh, gx = tx0 + (pxg & 15) + oh;
      *(uint4*)&yout[((size_t)(b * Ho + gy) * Wo + gx) * CT + coff + oc0 +
                     pass * (NF * 8) + ocq] = v;
    }
  }
}

// =================== 3x3 MFMA conv (halo input, dbuf LDS A, global B) ========
// LDS A layout per buffer: chunk index = q*384 + py*18 + px (q-slice padded
// 324->384 = 6 waves of 64 so global_load_lds dest stays base+lane*16).
template <int CINP, int NF>
__global__ __launch_bounds__(256, (NF <= 6 ? 3 : 2)) void mfma_conv3(
    const unsigned short* __restrict__ xin,  // [B][H+2][W+2][CINP] halo
    const unsigned short* __restrict__ wpk,  // [9][CINP/8][OCP][8]
    const float* __restrict__ bias, unsigned short* __restrict__ yout,
    int H, int W, int Cout, int OCP, int CT, int coff, int Wo, int oh) {
  const int Hp = H + 2, Wp = W + 2;
  constexpr int ICQS = CINP / 8;
  constexpr int NI = CINP / 32;
  __shared__ __align__(16) unsigned short smem[24576];  // 2 x 1536 chunks

  const int tid = threadIdx.x;
  const int wave = tid >> 6, lane = tid & 63;
  const int l15 = lane & 15, lq = lane >> 4;
  const int tilesX = W >> 4;
  const int perB = (H >> 4) * tilesX;
  const int b = blockIdx.x / perB;
  const int r0 = blockIdx.x % perB;
  const int ty0 = (r0 / tilesX) << 4;
  const int tx0 = (r0 % tilesX) << 4;
  const int oc0 = blockIdx.y * (NF * 16);

  f32x4 acc[4][NF];
#pragma unroll
  for (int mf = 0; mf < 4; ++mf)
#pragma unroll
    for (int nf = 0; nf < NF; ++nf) acc[mf][nf] = (f32x4){0.f, 0.f, 0.f, 0.f};

  // hoisted staging pointers: thread handles chunks e = tid + k*256
  const size_t rowbase = (size_t)(b * Hp + ty0) * Wp + tx0;
  const unsigned short* gp[6];
#pragma unroll
  for (int k = 0; k < 6; ++k) {
    int e = tid + k * 256;
    int q = e / 384;
    int r = e - q * 384;
    int rc = (r < 324) ? r : 323;  // pad lanes load a harmless valid chunk
    int py = rc / 18, px = rc - py * 18;
    gp[k] = xin + (rowbase + (size_t)py * Wp + px) * CINP + q * 8;
  }
  const unsigned short* wB = wpk + ((size_t)lq * OCP + oc0 + l15) * 8;
  const int icbStr = 4 * OCP * 8;
  const int tapStr = ICQS * OCP * 8;

  // double buffers at integer LDS offsets 0 / 12288 (ushorts)
  // prologue: stage icb 0 into buf 0
#pragma unroll
  for (int k = 0; k < 6; ++k)
    gload_lds16(gp[k], smem + (tid + k * 256) * 8);

  for (int icb = 0; icb < NI; ++icb) {
    const int curOff = (icb & 1) * 12288;
    __syncthreads();  // drains stage(cur); other buf free (read last iter)
    if (icb + 1 < NI) {
      const int nxtOff = curOff ^ 12288;
#pragma unroll
      for (int k = 0; k < 6; ++k)
        gload_lds16(gp[k] + (icb + 1) * 32,
                    smem + nxtOff + (tid + k * 256) * 8);
    }
    const unsigned short* wbi = wB + icb * icbStr;
#pragma unroll
    for (int tap = 0; tap < 9; ++tap) {
      const int dy = tap / 3, dx = tap - dy * 3;
      bf16x8 vb[NF], va[4];
#pragma unroll
      for (int nf = 0; nf < NF; ++nf)
        vb[nf] = *(const bf16x8*)&wbi[tap * tapStr + nf * 128];
#pragma unroll
      for (int mf = 0; mf < 4; ++mf)
        va[mf] = *(const bf16x8*)
            &smem[curOff +
                  (lq * 384 + (wave * 4 + mf + dy) * 18 + l15 + dx) * 8];
      __builtin_amdgcn_s_setprio(1);
#pragma unroll
      for (int mf = 0; mf < 4; ++mf)
#pragma unroll
        for (int nf = 0; nf < NF; ++nf)
          acc[mf][nf] = __builtin_amdgcn_mfma_f32_16x16x32_bf16(
              va[mf], vb[nf], acc[mf][nf], 0, 0, 0);
      __builtin_amdgcn_s_setprio(0);
    }
  }
  __syncthreads();  // epilogue slices overlap A buffers

  float bsv[NF];
#pragma unroll
  for (int nf = 0; nf < NF; ++nf) {
    int oc = oc0 + nf * 16 + l15;
    bsv[nf] = (oc < Cout) ? bias[oc] : 0.f;
  }
  unsigned short* slice = smem + wave * (NF * 512);
  const int Ho = H + 2 * oh;
#pragma unroll
  for (int pass = 0; pass < 2; ++pass) {
#pragma unroll
    for (int mf = 0; mf < 4; ++mf)
#pragma unroll
      for (int h = 0; h < NF / 2; ++h) {
        const int nf = pass * (NF / 2) + h;
#pragma unroll
        for (int r = 0; r < 4; ++r)
          slice[(mf * 16 + lq * 4 + r) * (NF * 8) + h * 16 + l15] =
              f2bf(fmaxf(acc[mf][nf][r] + bsv[nf], 0.f));
      }
#pragma unroll
    for (int j = 0; j < NF; ++j) {
      int c = j * 64 + lane;
      int pxl = c / NF;
      int ocq = (c - pxl * NF) * 8;
      uint4 v = *(uint4*)&slice[pxl * (NF * 8) + ocq];
      int pxg = wave * 64 + pxl;
      int gy = ty0 + (pxg >> 4) + oh, gx = tx0 + (pxg & 15) + oh;
      *(uint4*)&yout[((size_t)(b * Ho + gy) * Wo + gx) * CT + coff + oc0 +
                     pass * (NF * 8) + ocq] = v;
    }
  }
}

__global__ __launch_bounds__(256) void copy_flow(const float* __restrict__ flow,
                                                 float* __restrict__ out, int B,
                                                 int HW) {
  int q = HW / 4;
  int n = B * 2 * q;
  int i = blockIdx.x * blockDim.x + threadIdx.x;
  if (i < n) {
    float4 v = ((const float4*)flow)[i];
    int p = i % q;
    int t = i / q;
    int c = t % 2;
    int bb = t / 2;
    ((float4*)out)[((bb * 128 + 126 + c) * HW) / 4 + p] = v;
  }
}

extern "C" void kernel_launch(void* const* d_in, const int* in_sizes, int n_in,
                              void* d_out, int out_size, void* d_ws,
                              size_t ws_size, hipStream_t stream) {
  const float* flow = (const float*)d_in[0];
  const float* corr = (const float*)d_in[1];
  const float* wc1 = (const float*)d_in[2];
  const float* bc1 = (const float*)d_in[3];
  const float* wc2 = (const float*)d_in[4];
  const float* bc2 = (const float*)d_in[5];
  const float* wf1 = (const float*)d_in[6];
  const float* bf1 = (const float*)d_in[7];
  const float* wf2 = (const float*)d_in[8];
  const float* bf2 = (const float*)d_in[9];
  const float* wo = (const float*)d_in[10];
  const float* bo = (const float*)d_in[11];
  float* out = (float*)d_out;

  const int B = 8, H = 96, W = 128;
  const int HW = H * W;                 // 12288
  const size_t NPX = (size_t)B * HW;    // 98304

  char* ws = (char*)d_ws;
  // R0: corrT [NPX][352] bf16; then cat [8][98][130][256] bf16
  unsigned short* corrT = (unsigned short*)(ws + 0);
  unsigned short* cat = (unsigned short*)(ws + 0);
  // R1: buf1 [8][98][130][256]; then fcol [NPX][128] + out5
  unsigned short* buf1 = (unsigned short*)(ws + 69206016);
  unsigned short* fcol = (unsigned short*)(ws + 69206016);
  unsigned short* out5 = (unsigned short*)(ws + 69206016 + 25165824);
  // R2: flo1 [8][98][130][128]
  unsigned short* flo1 = (unsigned short*)(ws + 121389056);
  // weights
  unsigned short* p1 = (unsigned short*)(ws + 147480576);  // [1][44][256][8]
  unsigned short* p2 = (unsigned short*)(ws + 147660800);  // [9][32][192][8]
  unsigned short* p3 = (unsigned short*)(ws + 148545536);  // [9][16][64][8]
  unsigned short* p4 = (unsigned short*)(ws + 148692992);  // [9][32][128][8]
  unsigned short* pf1 = (unsigned short*)(ws + 149282816); // [16][128][8]

  // weight repacks
  repack_w_bf16<<<dim3(128), dim3(256), 0, stream>>>(wc1, p1, 256, 324, 1, 44, 256);
  repack_w_bf16<<<dim3(256), dim3(256), 0, stream>>>(wc2, p2, 192, 256, 9, 32, 192);
  repack_w_bf16<<<dim3(64), dim3(256), 0, stream>>>(wf2, p3, 64, 128, 9, 16, 64);
  repack_w_bf16<<<dim3(192), dim3(256), 0, stream>>>(wo, p4, 126, 256, 9, 32, 128);
  repack_wf1<<<dim3(64), dim3(256), 0, stream>>>(wf1, pf1);

  // corr NCHW f32 -> dense NHWC bf16 (ch padded 324->352)
  nchw2nhwc_bf16<<<dim3(NPX / 64, 6), dim3(256), 0, stream>>>(corr, corrT, 324,
                                                              352, HW);
  // conv1: 1x1 352->256 (128 oc/block), corrT -> buf1 (halo write)
  mfma_gemm<352, 8><<<dim3(384, 2), dim3(256), 0, stream>>>(
      corrT, p1, bc1, buf1, H, W, 256, 256, 256, 0, 130, 1);
  // zero halos of buf1, cat, flo1 (corrT dead now; cat aliases it)
  zero_halo3<<<dim3(512, 3), dim3(256), 0, stream>>>(buf1, cat, flo1);
  // conv2: 3x3 256->192 (96 oc/block), buf1 -> cat ch 0..191
  mfma_conv3<256, 6><<<dim3(384, 2), dim3(256), 0, stream>>>(
      buf1, p2, bc2, cat, H, W, 192, 192, 256, 0, 130, 1);
  // im2col flow (buf1 dead; fcol aliases it)
  im2col_flow<<<dim3(NPX * 16 / 256), dim3(256), 0, stream>>>(flow, fcol, H, W);
  // convf1 as 1x1 GEMM: 128(k)->128 in one block, fcol -> flo1 (halo write)
  mfma_gemm<128, 8><<<dim3(384, 1), dim3(256), 0, stream>>>(
      fcol, pf1, bf1, flo1, H, W, 128, 128, 128, 0, 130, 1);
  // convf2: 3x3 128->64 split 2x32 oc, flo1 -> cat ch 192..255
  mfma_conv3<128, 2><<<dim3(384, 2), dim3(256), 0, stream>>>(
      flo1, p3, bf2, cat, H, W, 64, 64, 256, 192, 130, 1);
  // conv5: 3x3 256->126 split 2x64 oc, cat -> out5 (dense)
  mfma_conv3<256, 4><<<dim3(384, 2), dim3(256), 0, stream>>>(
      cat, p4, bo, out5, H, W, 126, 128, 128, 0, 128, 0);
  // out5 -> out NCHW f32 ch 0..125; flow -> ch 126..127
  nhwc_bf16_2nchw<<<dim3(NPX / 64, 2), dim3(256), 0, stream>>>(out5, out, 128,
                                                               126, 128, HW);
  copy_flow<<<dim3(192), dim3(256), 0, stream>>>(flow, out, B, HW);
}

// Round 4
// 532.329 us; speedup vs baseline: 1.0287x; 1.0287x over previous
//
#include <hip/hip_runtime.h>

// BasicMotionEncoder (RAFT): B=8, H=96, W=128, CORR=324.
// Round 9 = round-0 config (best measured total, 529.3 us) + the single
// proven delta: s_setprio(1/0) around the MFMA clusters (conv2 A/B'd
// 122-128 -> 108.5 us under identical launch config in round 1).
// Reverted: all NF splits (conv5 <256,8> g(384,1), convf2 <128,4> g(384,1),
// convf1 <128,8> g(384,1)) and all launch_bounds back to (256,2) -- the
// lb3 squeeze cut arch VGPRs 96->84, losing tap-loop load ILP, and the 3rd
// resident block thrashed L2 (FETCH +57%): occupancy up, latency up, net loss.

typedef __bf16 bf16x8 __attribute__((ext_vector_type(8)));
typedef float f32x4 __attribute__((ext_vector_type(4)));

__device__ __forceinline__ unsigned short f2bf(float f) {
  __bf16 h = (__bf16)f;
  return __builtin_bit_cast(unsigned short, h);
}
__device__ __forceinline__ float bf2f(unsigned short u) {
  __bf16 h = __builtin_bit_cast(__bf16, u);
  return (float)h;
}

__device__ __forceinline__ void gload_lds16(const unsigned short* g,
                                            unsigned short* l) {
  __builtin_amdgcn_global_load_lds(
      (const __attribute__((address_space(1))) unsigned int*)g,
      (__attribute__((address_space(3))) unsigned int*)l, 16, 0, 0);
}

// ---------------- weight repack: OIHW f32 -> [tap][icq][OCP][8] bf16 ---------
__global__ __launch_bounds__(256) void repack_w_bf16(
    const float* __restrict__ w, unsigned short* __restrict__ dst, int O, int I,
    int K2, int ICQ, int OCP) {
  int n = K2 * ICQ * OCP * 8;
  for (int s = blockIdx.x * 256 + threadIdx.x; s < n; s += gridDim.x * 256) {
    int j = s & 7;
    int r = s >> 3;
    int oc = r % OCP;
    r /= OCP;
    int icq = r % ICQ;
    int tap = r / ICQ;
    int ic = icq * 8 + j;
    float v = (oc < O && ic < I) ? w[((size_t)oc * I + ic) * K2 + tap] : 0.f;
    dst[s] = f2bf(v);
  }
}

// wf1 [128][2][7][7] -> [kq=16][128][8], k = ic*49 + dy*7 + dx, pad 98->128
__global__ __launch_bounds__(256) void repack_wf1(const float* __restrict__ w,
                                                  unsigned short* __restrict__ dst) {
  int s = blockIdx.x * 256 + threadIdx.x;
  if (s >= 16384) return;
  int j = s & 7;
  int oc = (s >> 3) & 127;
  int kq = s >> 10;
  int k = kq * 8 + j;
  float v = 0.f;
  if (k < 98) {
    int ic = k / 49;
    int tap = k - ic * 49;
    v = w[(oc * 2 + ic) * 49 + tap];
  }
  dst[s] = f2bf(v);
}

// ------------- NCHW f32 -> NHWC bf16 (zero-padded channels) ------------------
__global__ __launch_bounds__(256) void nchw2nhwc_bf16(
    const float* __restrict__ in, unsigned short* __restrict__ outp, int C,
    int CP, int HW) {
  __shared__ float sls[64][65];
  int p0 = blockIdx.x * 64;
  int c0 = blockIdx.y * 64;
  int b = p0 / HW, hw0 = p0 % HW;
  int tid = threadIdx.x;
  for (int e = tid; e < 4096; e += 256) {
    int ch = e >> 6, px = e & 63;
    float v = 0.f;
    if (c0 + ch < C) v = in[(size_t)(b * C + c0 + ch) * HW + hw0 + px];
    sls[px][ch] = v;
  }
  __syncthreads();
  for (int e = tid; e < 512; e += 256) {
    int px = e >> 3, cc = e & 7;
    if (c0 + cc * 8 < CP) {
      unsigned short pk[8];
#pragma unroll
      for (int j = 0; j < 8; ++j) pk[j] = f2bf(sls[px][cc * 8 + j]);
      *(uint4*)&outp[(size_t)(p0 + px) * CP + c0 + cc * 8] = *(uint4*)pk;
    }
  }
}

// ------------- NHWC bf16 -> NCHW f32 (channels < CO only) --------------------
__global__ __launch_bounds__(256) void nhwc_bf16_2nchw(
    const unsigned short* __restrict__ inp, float* __restrict__ outp, int CP,
    int CO, int CT, int HW) {
  __shared__ float sls[64][65];
  int p0 = blockIdx.x * 64, c0 = blockIdx.y * 64;
  int b = p0 / HW, hw0 = p0 % HW;
  int tid = threadIdx.x;
  for (int e = tid; e < 512; e += 256) {
    int px = e >> 3, cc = e & 7;
    uint4 v = *(const uint4*)&inp[(size_t)(p0 + px) * CP + c0 + cc * 8];
    unsigned short* ps = (unsigned short*)&v;
#pragma unroll
    for (int j = 0; j < 8; ++j) sls[px][cc * 8 + j] = bf2f(ps[j]);
  }
  __syncthreads();
  for (int e = tid; e < 1024; e += 256) {
    int ch = e >> 4, pq = e & 15;
    if (c0 + ch < CO) {
      float4 v;
      v.x = sls[pq * 4 + 0][ch];
      v.y = sls[pq * 4 + 1][ch];
      v.z = sls[pq * 4 + 2][ch];
      v.w = sls[pq * 4 + 3][ch];
      *(float4*)&outp[(size_t)(b * CT + c0 + ch) * HW + hw0 + pq * 4] = v;
    }
  }
}

// ------------- zero the 1-px halo border of the 3 padded buffers -------------
__global__ __launch_bounds__(256) void zero_halo3(unsigned short* b0,
                                                  unsigned short* b1,
                                                  unsigned short* b2) {
  unsigned short* buf = (blockIdx.y == 0) ? b0 : (blockIdx.y == 1) ? b1 : b2;
  const int C = (blockIdx.y == 2) ? 128 : 256;
  const int cq = C >> 3;
  int n = 8 * 452 * cq;
  int i = blockIdx.x * 256 + threadIdx.x;
  if (i >= n) return;
  int c = i % cq;
  int t = i / cq;
  int bp = t % 452;
  int bb = t / 452;
  int y, x;
  if (bp < 130) { y = 0; x = bp; }
  else if (bp < 260) { y = 97; x = bp - 130; }
  else { int r = bp - 260; y = 1 + (r >> 1); x = (r & 1) ? 129 : 0; }
  *(uint4*)&buf[((size_t)(bb * 98 + y) * 130 + x) * C + c * 8] =
      make_uint4(0, 0, 0, 0);
}

// ------------- im2col of flow: [8][2][96][128] f32 -> [NPX][128] bf16 --------
__global__ __launch_bounds__(256) void im2col_flow(const float* __restrict__ f,
                                                   unsigned short* __restrict__ o,
                                                   int H, int W) {
  int s = blockIdx.x * 256 + threadIdx.x;  // over NPX*16
  int kq = s & 15;
  int px = s >> 4;
  int HW = H * W;
  int b = px / HW;
  int r = px % HW;
  int y = r / W;
  int x = r % W;
  unsigned short pk[8];
#pragma unroll
  for (int j = 0; j < 8; ++j) {
    int k = kq * 8 + j;
    float v = 0.f;
    if (k < 98) {
      int ic = k / 49;
      int t = k - ic * 49;
      int dy = t / 7, dx = t - dy * 7;
      int yy = y + dy - 3, xx = x + dx - 3;
      if (yy >= 0 && yy < H && xx >= 0 && xx < W)
        v = f[((size_t)(b * 2 + ic) * H + yy) * W + xx];
    }
    pk[j] = f2bf(v);
  }
  *(uint4*)&o[(size_t)px * 128 + kq * 8] = *(uint4*)pk;
}

// =================== 1x1 MFMA GEMM (no LDS staging, no barriers) =============
// Block: 256 px x NF*16 oc; 4 waves x (64px x NF*16oc).
template <int CINP, int NF>
__global__ __launch_bounds__(256, 2) void mfma_gemm(
    const unsigned short* __restrict__ xin,  // [B*H*W][CINP]
    const unsigned short* __restrict__ wpk,  // [CINP/8][OCP][8]
    const float* __restrict__ bias, unsigned short* __restrict__ yout,
    int H, int W, int Cout, int OCP, int CT, int coff, int Wo, int oh) {
  __shared__ __align__(16) unsigned short smem[NF * 2048];
  const int tid = threadIdx.x;
  const int wave = tid >> 6, lane = tid & 63;
  const int l15 = lane & 15, lq = lane >> 4;
  const int tilesX = W >> 4;
  const int perB = (H >> 4) * tilesX;
  const int b = blockIdx.x / perB;
  const int r0 = blockIdx.x % perB;
  const int ty0 = (r0 / tilesX) << 4;
  const int tx0 = (r0 % tilesX) << 4;
  const int oc0 = blockIdx.y * (NF * 16);

  f32x4 acc[4][NF];
#pragma unroll
  for (int mf = 0; mf < 4; ++mf)
#pragma unroll
    for (int nf = 0; nf < NF; ++nf) acc[mf][nf] = (f32x4){0.f, 0.f, 0.f, 0.f};

  size_t rowA[4];
#pragma unroll
  for (int mf = 0; mf < 4; ++mf)
    rowA[mf] =
        ((size_t)(b * H + ty0 + wave * 4 + mf) * W + tx0 + l15) * CINP + lq * 8;
  const unsigned short* wB = wpk + ((size_t)lq * OCP + oc0 + l15) * 8;
  const int icbStr = 4 * OCP * 8;

  constexpr int NI = CINP / 32;
#pragma unroll 2
  for (int icb = 0; icb < NI; ++icb) {
    bf16x8 va[4], vb[NF];
#pragma unroll
    for (int mf = 0; mf < 4; ++mf)
      va[mf] = *(const bf16x8*)&xin[rowA[mf] + icb * 32];
#pragma unroll
    for (int nf = 0; nf < NF; ++nf)
      vb[nf] = *(const bf16x8*)&wB[icb * icbStr + nf * 128];
    __builtin_amdgcn_s_setprio(1);
#pragma unroll
    for (int mf = 0; mf < 4; ++mf)
#pragma unroll
      for (int nf = 0; nf < NF; ++nf)
        acc[mf][nf] = __builtin_amdgcn_mfma_f32_16x16x32_bf16(
            va[mf], vb[nf], acc[mf][nf], 0, 0, 0);
    __builtin_amdgcn_s_setprio(0);
  }

  // two-pass epilogue: bias+relu, per-wave LDS transpose, 16B stores
  float bsv[NF];
#pragma unroll
  for (int nf = 0; nf < NF; ++nf) {
    int oc = oc0 + nf * 16 + l15;
    bsv[nf] = (oc < Cout) ? bias[oc] : 0.f;
  }
  unsigned short* slice = smem + wave * (NF * 512);
  const int Ho = H + 2 * oh;
#pragma unroll
  for (int pass = 0; pass < 2; ++pass) {
#pragma unroll
    for (int mf = 0; mf < 4; ++mf)
#pragma unroll
      for (int h = 0; h < NF / 2; ++h) {
        const int nf = pass * (NF / 2) + h;
#pragma unroll
        for (int r = 0; r < 4; ++r)
          slice[(mf * 16 + lq * 4 + r) * (NF * 8) + h * 16 + l15] =
              f2bf(fmaxf(acc[mf][nf][r] + bsv[nf], 0.f));
      }
#pragma unroll
    for (int j = 0; j < NF; ++j) {
      int c = j * 64 + lane;
      int pxl = c / NF;
      int ocq = (c - pxl * NF) * 8;
      uint4 v = *(uint4*)&slice[pxl * (NF * 8) + ocq];
      int pxg = wave * 64 + pxl;
      int gy = ty0 + (pxg >> 4) + oh, gx = tx0 + (pxg & 15) + oh;
      *(uint4*)&yout[((size_t)(b * Ho + gy) * Wo + gx) * CT + coff + oc0 +
                     pass * (NF * 8) + ocq] = v;
    }
  }
}

// =================== 3x3 MFMA conv (halo input, dbuf LDS A, global B) ========
// LDS A layout per buffer: chunk index = q*384 + py*18 + px (q-slice padded
// 324->384 = 6 waves of 64 so global_load_lds dest stays base+lane*16).
template <int CINP, int NF>
__global__ __launch_bounds__(256, 2) void mfma_conv3(
    const unsigned short* __restrict__ xin,  // [B][H+2][W+2][CINP] halo
    const unsigned short* __restrict__ wpk,  // [9][CINP/8][OCP][8]
    const float* __restrict__ bias, unsigned short* __restrict__ yout,
    int H, int W, int Cout, int OCP, int CT, int coff, int Wo, int oh) {
  const int Hp = H + 2, Wp = W + 2;
  constexpr int ICQS = CINP / 8;
  constexpr int NI = CINP / 32;
  __shared__ __align__(16) unsigned short smem[24576];  // 2 x 1536 chunks

  const int tid = threadIdx.x;
  const int wave = tid >> 6, lane = tid & 63;
  const int l15 = lane & 15, lq = lane >> 4;
  const int tilesX = W >> 4;
  const int perB = (H >> 4) * tilesX;
  const int b = blockIdx.x / perB;
  const int r0 = blockIdx.x % perB;
  const int ty0 = (r0 / tilesX) << 4;
  const int tx0 = (r0 % tilesX) << 4;
  const int oc0 = blockIdx.y * (NF * 16);

  f32x4 acc[4][NF];
#pragma unroll
  for (int mf = 0; mf < 4; ++mf)
#pragma unroll
    for (int nf = 0; nf < NF; ++nf) acc[mf][nf] = (f32x4){0.f, 0.f, 0.f, 0.f};

  // hoisted staging pointers: thread handles chunks e = tid + k*256
  const size_t rowbase = (size_t)(b * Hp + ty0) * Wp + tx0;
  const unsigned short* gp[6];
#pragma unroll
  for (int k = 0; k < 6; ++k) {
    int e = tid + k * 256;
    int q = e / 384;
    int r = e - q * 384;
    int rc = (r < 324) ? r : 323;  // pad lanes load a harmless valid chunk
    int py = rc / 18, px = rc - py * 18;
    gp[k] = xin + (rowbase + (size_t)py * Wp + px) * CINP + q * 8;
  }
  const unsigned short* wB = wpk + ((size_t)lq * OCP + oc0 + l15) * 8;
  const int icbStr = 4 * OCP * 8;
  const int tapStr = ICQS * OCP * 8;

  // double buffers at integer LDS offsets 0 / 12288 (ushorts)
  // prologue: stage icb 0 into buf 0
#pragma unroll
  for (int k = 0; k < 6; ++k)
    gload_lds16(gp[k], smem + (tid + k * 256) * 8);

  for (int icb = 0; icb < NI; ++icb) {
    const int curOff = (icb & 1) * 12288;
    __syncthreads();  // drains stage(cur); other buf free (read last iter)
    if (icb + 1 < NI) {
      const int nxtOff = curOff ^ 12288;
#pragma unroll
      for (int k = 0; k < 6; ++k)
        gload_lds16(gp[k] + (icb + 1) * 32,
                    smem + nxtOff + (tid + k * 256) * 8);
    }
    const unsigned short* wbi = wB + icb * icbStr;
#pragma unroll
    for (int tap = 0; tap < 9; ++tap) {
      const int dy = tap / 3, dx = tap - dy * 3;
      bf16x8 vb[NF], va[4];
#pragma unroll
      for (int nf = 0; nf < NF; ++nf)
        vb[nf] = *(const bf16x8*)&wbi[tap * tapStr + nf * 128];
#pragma unroll
      for (int mf = 0; mf < 4; ++mf)
        va[mf] = *(const bf16x8*)
            &smem[curOff +
                  (lq * 384 + (wave * 4 + mf + dy) * 18 + l15 + dx) * 8];
      __builtin_amdgcn_s_setprio(1);
#pragma unroll
      for (int mf = 0; mf < 4; ++mf)
#pragma unroll
        for (int nf = 0; nf < NF; ++nf)
          acc[mf][nf] = __builtin_amdgcn_mfma_f32_16x16x32_bf16(
              va[mf], vb[nf], acc[mf][nf], 0, 0, 0);
      __builtin_amdgcn_s_setprio(0);
    }
  }
  __syncthreads();  // epilogue slices overlap A buffers

  float bsv[NF];
#pragma unroll
  for (int nf = 0; nf < NF; ++nf) {
    int oc = oc0 + nf * 16 + l15;
    bsv[nf] = (oc < Cout) ? bias[oc] : 0.f;
  }
  unsigned short* slice = smem + wave * (NF * 512);
  const int Ho = H + 2 * oh;
#pragma unroll
  for (int pass = 0; pass < 2; ++pass) {
#pragma unroll
    for (int mf = 0; mf < 4; ++mf)
#pragma unroll
      for (int h = 0; h < NF / 2; ++h) {
        const int nf = pass * (NF / 2) + h;
#pragma unroll
        for (int r = 0; r < 4; ++r)
          slice[(mf * 16 + lq * 4 + r) * (NF * 8) + h * 16 + l15] =
              f2bf(fmaxf(acc[mf][nf][r] + bsv[nf], 0.f));
      }
#pragma unroll
    for (int j = 0; j < NF; ++j) {
      int c = j * 64 + lane;
      int pxl = c / NF;
      int ocq = (c - pxl * NF) * 8;
      uint4 v = *(uint4*)&slice[pxl * (NF * 8) + ocq];
      int pxg = wave * 64 + pxl;
      int gy = ty0 + (pxg >> 4) + oh, gx = tx0 + (pxg & 15) + oh;
      *(uint4*)&yout[((size_t)(b * Ho + gy) * Wo + gx) * CT + coff + oc0 +
                     pass * (NF * 8) + ocq] = v;
    }
  }
}

__global__ __launch_bounds__(256) void copy_flow(const float* __restrict__ flow,
                                                 float* __restrict__ out, int B,
                                                 int HW) {
  int q = HW / 4;
  int n = B * 2 * q;
  int i = blockIdx.x * blockDim.x + threadIdx.x;
  if (i < n) {
    float4 v = ((const float4*)flow)[i];
    int p = i % q;
    int t = i / q;
    int c = t % 2;
    int bb = t / 2;
    ((float4*)out)[((bb * 128 + 126 + c) * HW) / 4 + p] = v;
  }
}

extern "C" void kernel_launch(void* const* d_in, const int* in_sizes, int n_in,
                              void* d_out, int out_size, void* d_ws,
                              size_t ws_size, hipStream_t stream) {
  const float* flow = (const float*)d_in[0];
  const float* corr = (const float*)d_in[1];
  const float* wc1 = (const float*)d_in[2];
  const float* bc1 = (const float*)d_in[3];
  const float* wc2 = (const float*)d_in[4];
  const float* bc2 = (const float*)d_in[5];
  const float* wf1 = (const float*)d_in[6];
  const float* bf1 = (const float*)d_in[7];
  const float* wf2 = (const float*)d_in[8];
  const float* bf2 = (const float*)d_in[9];
  const float* wo = (const float*)d_in[10];
  const float* bo = (const float*)d_in[11];
  float* out = (float*)d_out;

  const int B = 8, H = 96, W = 128;
  const int HW = H * W;                 // 12288
  const size_t NPX = (size_t)B * HW;    // 98304

  char* ws = (char*)d_ws;
  // R0: corrT [NPX][352] bf16; then cat [8][98][130][256] bf16
  unsigned short* corrT = (unsigned short*)(ws + 0);
  unsigned short* cat = (unsigned short*)(ws + 0);
  // R1: buf1 [8][98][130][256]; then fcol [NPX][128] + out5
  unsigned short* buf1 = (unsigned short*)(ws + 69206016);
  unsigned short* fcol = (unsigned short*)(ws + 69206016);
  unsigned short* out5 = (unsigned short*)(ws + 69206016 + 25165824);
  // R2: flo1 [8][98][130][128]
  unsigned short* flo1 = (unsigned short*)(ws + 121389056);
  // weights
  unsigned short* p1 = (unsigned short*)(ws + 147480576);  // [1][44][256][8]
  unsigned short* p2 = (unsigned short*)(ws + 147660800);  // [9][32][192][8]
  unsigned short* p3 = (unsigned short*)(ws + 148545536);  // [9][16][64][8]
  unsigned short* p4 = (unsigned short*)(ws + 148692992);  // [9][32][128][8]
  unsigned short* pf1 = (unsigned short*)(ws + 149282816); // [16][128][8]

  // weight repacks
  repack_w_bf16<<<dim3(128), dim3(256), 0, stream>>>(wc1, p1, 256, 324, 1, 44, 256);
  repack_w_bf16<<<dim3(256), dim3(256), 0, stream>>>(wc2, p2, 192, 256, 9, 32, 192);
  repack_w_bf16<<<dim3(64), dim3(256), 0, stream>>>(wf2, p3, 64, 128, 9, 16, 64);
  repack_w_bf16<<<dim3(192), dim3(256), 0, stream>>>(wo, p4, 126, 256, 9, 32, 128);
  repack_wf1<<<dim3(64), dim3(256), 0, stream>>>(wf1, pf1);

  // corr NCHW f32 -> dense NHWC bf16 (ch padded 324->352)
  nchw2nhwc_bf16<<<dim3(NPX / 64, 6), dim3(256), 0, stream>>>(corr, corrT, 324,
                                                              352, HW);
  // conv1: 1x1 352->256 (128 oc/block), corrT -> buf1 (halo write)
  mfma_gemm<352, 8><<<dim3(384, 2), dim3(256), 0, stream>>>(
      corrT, p1, bc1, buf1, H, W, 256, 256, 256, 0, 130, 1);
  // zero halos of buf1, cat, flo1 (corrT dead now; cat aliases it)
  zero_halo3<<<dim3(512, 3), dim3(256), 0, stream>>>(buf1, cat, flo1);
  // conv2: 3x3 256->192 (96 oc/block), buf1 -> cat ch 0..191
  mfma_conv3<256, 6><<<dim3(384, 2), dim3(256), 0, stream>>>(
      buf1, p2, bc2, cat, H, W, 192, 192, 256, 0, 130, 1);
  // im2col flow (buf1 dead; fcol aliases it)
  im2col_flow<<<dim3(NPX * 16 / 256), dim3(256), 0, stream>>>(flow, fcol, H, W);
  // convf1 as 1x1 GEMM: 128(k)->128, fcol -> flo1 (halo write)
  mfma_gemm<128, 8><<<dim3(384, 1), dim3(256), 0, stream>>>(
      fcol, pf1, bf1, flo1, H, W, 128, 128, 128, 0, 130, 1);
  // convf2: 3x3 128->64, flo1 -> cat ch 192..255
  mfma_conv3<128, 4><<<dim3(384, 1), dim3(256), 0, stream>>>(
      flo1, p3, bf2, cat, H, W, 64, 64, 256, 192, 130, 1);
  // conv5: 3x3 256->126 (128 oc/block), cat -> out5 (dense)
  mfma_conv3<256, 8><<<dim3(384, 1), dim3(256), 0, stream>>>(
      cat, p4, bo, out5, H, W, 126, 128, 128, 0, 128, 0);
  // out5 -> out NCHW f32 ch 0..125; flow -> ch 126..127
  nhwc_bf16_2nchw<<<dim3(NPX / 64, 2), dim3(256), 0, stream>>>(out5, out, 128,
                                                               126, 128, HW);
  copy_flow<<<dim3(192), dim3(256), 0, stream>>>(flow, out, B, HW);
}